// Round 1
// baseline (399.280 us; speedup 1.0000x reference)
//
#include <hip/hip_runtime.h>

// Stochastic LIF neuron scan, fp32, shapes B=32, T=16, N=65536.
//   u = 0.5*u + x[t]; u -= noise[t];
//   p = clip((u - 1.0 + 0.4)/0.8, 0, 1); o = (unif[t] < p); u *= (1-o)
// Memory-bound: 512 MiB total HBM traffic -> ~85us floor at 6.3 TB/s.
//
// R1: 166us rolled loop, vmcnt(0) each t. R2: 2 scans/thread + 1-deep
// prefetch -> ~150us (rocprof), but only 4 waves/SIMD (Occupancy 38%),
// VALUBusy 11% -> latency-bound, not BW-bound.
// R3 (this): 1 scan/thread -> 2048 blocks, 8 blocks/CU, 8 waves/SIMD
// (VGPR ~40 <= 64). Double the TLP to fill vmcnt stall windows; plus
// non-temporal stores so the write-only output doesn't evict input
// lines from L2/Infinity Cache (inputs 384MB vs 256MB LLC).

namespace {

constexpr int B = 32;
constexpr int T = 16;
constexpr int N = 65536;
constexpr int N4 = N / 4;            // 16384 float4 per (b,t) row
constexpr int N4_SHIFT = 14;         // log2(N4)

constexpr float SIGMA = 0.4f;        // A
constexpr float TWO_SIGMA = 0.8f;    // 2*A
constexpr float THRESHOLD = 1.0f;
constexpr float TAU_INV = 0.5f;

typedef float floatv4 __attribute__((ext_vector_type(4)));

// One timestep, one scalar element. Must match reference fp32 op order:
// mul+add (0.5*u exact, fma-safe), sub, sub, add, IEEE divide (do NOT
// fold to *1.25f), clamp, compare, mul.
__device__ __forceinline__ float lif_step(float& u, float xi, float ni, float ri) {
    u = TAU_INV * u + xi;            // leaky integrate
    u = u - ni;                      // noise injection
    float v = u - THRESHOLD;
    float p = (v + SIGMA) / TWO_SIGMA;  // IEEE fp32 divide
    p = fminf(fmaxf(p, 0.0f), 1.0f);
    float o = (ri < p) ? 1.0f : 0.0f;
    u = u * (1.0f - o);              // hard reset where spiked
    return o;
}

__device__ __forceinline__ float4 lif_step4(float4& u, const float4& xi,
                                            const float4& ni, const float4& ri) {
    float4 o;
    o.x = lif_step(u.x, xi.x, ni.x, ri.x);
    o.y = lif_step(u.y, xi.y, ni.y, ri.y);
    o.z = lif_step(u.z, xi.z, ni.z, ri.z);
    o.w = lif_step(u.w, xi.w, ni.w, ri.w);
    return o;
}

__device__ __forceinline__ void store_nt(float4* p, const float4& v) {
    __builtin_nontemporal_store(*(const floatv4*)&v, (floatv4*)p);
}

__global__ __launch_bounds__(256) void snn_scan_kernel(
    const float4* __restrict__ x,
    const float4* __restrict__ noise,
    const float4* __restrict__ unif,
    float4* __restrict__ out)
{
    const int tid = blockIdx.x * blockDim.x + threadIdx.x;   // [0, B * N4)
    const int b = tid >> N4_SHIFT;                           // 0..31
    const int nc = tid & (N4 - 1);

    int idx = b * T * N4 + nc;

    float4 u = make_float4(0.f, 0.f, 0.f, 0.f);

    // prologue: load t=0
    float4 cx = x[idx], cn = noise[idx], cr = unif[idx];

    #pragma unroll 1   // keep the 1-deep pipeline shape; don't let full
                       // unroll balloon VGPRs past the 64-reg/8-wave cliff
    for (int t = 0; t < T - 1; ++t) {
        const int nidx = idx + N4;
        // issue t+1 loads before computing t
        float4 nx = x[nidx], nn = noise[nidx], nr = unif[nidx];

        float4 o = lif_step4(u, cx, cn, cr);
        store_nt(&out[idx], o);

        cx = nx; cn = nn; cr = nr;
        idx = nidx;
    }

    // epilogue: last timestep
    float4 o = lif_step4(u, cx, cn, cr);
    store_nt(&out[idx], o);
}

} // namespace

extern "C" void kernel_launch(void* const* d_in, const int* in_sizes, int n_in,
                              void* d_out, int out_size, void* d_ws, size_t ws_size,
                              hipStream_t stream) {
    const float4* x     = (const float4*)d_in[0];
    const float4* noise = (const float4*)d_in[1];
    const float4* unif  = (const float4*)d_in[2];
    float4* out         = (float4*)d_out;

    const int threads_total = B * N4;            // 524288 (1 scan/thread)
    const int block = 256;
    const int grid = threads_total / block;      // 2048 blocks, 8/CU

    snn_scan_kernel<<<grid, block, 0, stream>>>(x, noise, unif, out);
}